// Round 8
// baseline (453.441 us; speedup 1.0000x reference)
//
#include <hip/hip_runtime.h>
#include <hip/hip_bf16.h>

#define N_NODES 50000
#define N_EDGES 800000
#define NEG_SLOPE 0.2f

typedef __hip_bfloat16 bf16;
typedef __attribute__((ext_vector_type(8))) short short8;
typedef __attribute__((ext_vector_type(4))) float f32x4;
typedef __attribute__((ext_vector_type(2))) float f32x2;

__device__ __forceinline__ float b2f(bf16 x) { return __bfloat162float(x); }

// flag: 1 = float tensors in d_in/d_out are bf16; 0 = fp32.
__device__ __forceinline__ float ldsel(const void* p, size_t i, int isbf) {
  return isbf ? __bfloat162float(((const bf16*)p)[i]) : ((const float*)p)[i];
}
__device__ __forceinline__ void stsel(void* p, size_t i, int isbf, float v) {
  if (isbf) ((bf16*)p)[i] = __float2bfloat16(v);
  else ((float*)p)[i] = v;
}

// per-block dtype detection (256 threads sample 256 even shorts of W_peg)
__device__ __forceinline__ int block_detect(const unsigned short* __restrict__ probe) {
  __shared__ int wcount;
  int tid = threadIdx.x;
  if (tid == 0) wcount = 0;
  __syncthreads();
  int ex = (probe[2 * tid] >> 7) & 0xFF;
  unsigned long long m = __ballot(ex >= 0x85);
  if ((tid & 63) == 0) atomicAdd(&wcount, __popcll(m));
  __syncthreads();
  return wcount < 8;
}

// ---------------- merged prep: dtype flag + 10 small cvts + 2 weight
// transposes + edge histogram (blocks >= 400).
struct CvtJobs {
  const void* src[10];
  float* dst[10];
  int n[10];
};
__global__ __launch_bounds__(256) void prep_kernel(CvtJobs jobs,
                                                   const unsigned short* __restrict__ probe,
                                                   const void* __restrict__ W0in,
                                                   bf16* __restrict__ Wt0,
                                                   const void* __restrict__ W1in,
                                                   bf16* __restrict__ Wt1,
                                                   int* __restrict__ flag,
                                                   const int* __restrict__ dst,
                                                   int* __restrict__ deg) {
  int tid = threadIdx.x;
  int b = blockIdx.x;
  if (b >= 400) {  // histogram part
    int e = (b - 400) * 256 + tid;
    atomicAdd(&deg[dst[e]], 1);
    return;
  }
  int isbf = block_detect(probe);
  if (b == 0 && tid == 0) *flag = isbf;
  if (b < 16) {
    for (int j = 0; j < 10; j++) {
      int n = jobs.n[j];
      const void* s = jobs.src[j];
      float* d = jobs.dst[j];
      for (int i = b * 256 + tid; i < n; i += 16 * 256) d[i] = ldsel(s, i, isbf);
    }
  } else if (b < 16 + 128) {
    int i = (b - 16) * 256 + tid;  // [0, 32768): Wt0 [256][128]
    int n = i >> 7, k = i & 127;
    Wt0[i] = __float2bfloat16(ldsel(W0in, (size_t)k * 256 + n, isbf));
  } else {
    int i = (b - 144) * 256 + tid;  // [0, 65536): Wt1 [256][256]
    int n = i >> 8, k = i & 255;
    Wt1[i] = __float2bfloat16(ldsel(W1in, (size_t)k * 256 + n, isbf));
  }
}

// ---------------- single-dispatch CSR scan: per-block scan, last block
// finalizes the 49 block sums (all cross-block traffic via device-scope
// atomics), everyone spins on flags[1]. 49 blocks — trivially co-resident.
__global__ __launch_bounds__(1024) void scan_kernel(const int* __restrict__ deg,
                                                    int* __restrict__ rowptr,
                                                    int* __restrict__ bsum,
                                                    int* __restrict__ flags, int n) {
  __shared__ int wsum[16];
  __shared__ int spre;
  int tid = threadIdx.x;
  int idx = blockIdx.x * 1024 + tid;
  int v = (idx < n) ? deg[idx] : 0;
  int incl = v;
#pragma unroll
  for (int off = 1; off < 64; off <<= 1) {
    int t = __shfl_up(incl, off);
    if ((tid & 63) >= off) incl += t;
  }
  int wid = tid >> 6;
  if ((tid & 63) == 63) wsum[wid] = incl;
  __syncthreads();
  if (tid == 0) {
    int acc = 0;
#pragma unroll
    for (int w = 0; w < 16; w++) {
      int t = wsum[w];
      wsum[w] = acc;
      acc += t;
    }
    atomicExch(&bsum[blockIdx.x], acc);
    if (atomicAdd(&flags[0], 1) == 48) {  // last publisher finalizes
      int a = 0;
      for (int j = 0; j < 49; j++) {
        int t = atomicAdd(&bsum[j], 0);
        atomicExch(&bsum[j], a);
        a += t;
      }
      atomicExch(&flags[1], 1);
    }
    while (atomicAdd(&flags[1], 0) == 0) {}
    spre = atomicAdd(&bsum[blockIdx.x], 0);
  }
  __syncthreads();
  if (idx < n) rowptr[idx + 1] = spre + wsum[wid] + incl;
  if (idx == 0) rowptr[0] = 0;
}

// ---------------- merged CSR-fill + PEG chains.
// blocks [0, 25000): XCD-partitioned CSR fill (block b covers edge chunk
// b>>3, commits only dst in XCD (b&7)'s node range -> csr line writes
// merge in one L2). blocks [25000, 25000+12500): PEG chains, 8 nodes/block.
#define NCHUNK (N_EDGES / 256)   // 3125
#define NFILL8 (NCHUNK * 8)      // 25000
#define NDIV8 (N_NODES / 8)      // 6250
__global__ __launch_bounds__(256) void fill_peg_kernel(const int* __restrict__ src,
                                                       const int* __restrict__ dst,
                                                       const int* __restrict__ rowptr,
                                                       int* __restrict__ fill,
                                                       int* __restrict__ csr_src,
                                                       const void* __restrict__ pen,
                                                       const void* __restrict__ pem,
                                                       const float* __restrict__ Wpeg,
                                                       const float* __restrict__ bpeg,
                                                       const float* __restrict__ Wu0,
                                                       const float* __restrict__ Wu1,
                                                       void* out, size_t out_off,
                                                       char* __restrict__ blob0,
                                                       char* __restrict__ blob1,
                                                       const int* __restrict__ flag) {
  __shared__ float w1[1024], w2[1024], w3[1024];
  __shared__ float rowA[256], rowB[256];
  int tid = threadIdx.x;
  int b = blockIdx.x;
  if (b < NFILL8) {  // XCD-partitioned CSR fill
    int xcd = b & 7;
    int e = (b >> 3) * 256 + tid;
    int d = dst[e];
    int lo = xcd * NDIV8;
    if (d >= lo && d < lo + NDIV8) {
      int pos = atomicAdd(&fill[d], 1);
      csr_src[rowptr[d] + pos] = src[e];
    }
    return;
  }
  int pb = b - NFILL8;
  int isbf = *flag;
  bool c3 = pb < NDIV8;
  int n0 = (c3 ? pb : pb - NDIV8) * 8;
  const void* in = c3 ? pen : pem;
  for (int i = tid; i < 1024; i += 256) {
    w1[i] = Wpeg[i];
    w2[i] = Wu0[i];
    if (c3) w3[i] = Wu1[i];
  }
  rowA[tid] = ldsel(in, (size_t)n0 * 32 + tid, isbf);
  __syncthreads();
  int col = tid & 31, ln = tid >> 5;
  size_t bi = ((size_t)(n0 + ln)) * 64 + col;  // bf16 index, stride 64 (=128B)
  float acc = bpeg[col];
#pragma unroll
  for (int j = 0; j < 32; j++) acc += rowA[ln * 32 + j] * w1[j * 32 + col];
  acc = fmaxf(acc, 0.f);
  if (!c3) ((bf16*)blob0)[bi] = __float2bfloat16(acc);
  rowB[tid] = acc;
  __syncthreads();
  acc = 0.f;
#pragma unroll
  for (int j = 0; j < 32; j++) acc += rowB[ln * 32 + j] * w2[j * 32 + col];
  acc = fmaxf(acc, 0.f);
  if (!c3) {
    ((bf16*)blob1)[bi] = __float2bfloat16(acc);
    return;
  }
  rowA[tid] = acc;
  __syncthreads();
  acc = 0.f;
#pragma unroll
  for (int j = 0; j < 32; j++) acc += rowA[ln * 32 + j] * w3[j * 32 + col];
  stsel(out, out_off + (size_t)n0 * 32 + tid, isbf, fmaxf(acc, 0.f));
}

// ---------------- MFMA feature GEMM + fused al_s/al_d epilogue.
// C[M,256] = A[M,K] @ B[K,256]; BK=128 / LDK=136 (conflict-free, measured).
// XCD-grouped tile remap: 4 col-tiles of a row tile on the same XCD.
// al_s -> blob [64,80) of the 128B node record; al_d -> its own array.
template <int K, bool A_DUAL>
__global__ __launch_bounds__(256) void mfma_gemm(const void* __restrict__ Ap,
                                                 const bf16* __restrict__ Bt,
                                                 bf16* __restrict__ C, int M,
                                                 const float* __restrict__ a_sf,
                                                 const float* __restrict__ a_df,
                                                 char* __restrict__ blob,
                                                 float* __restrict__ al_d,
                                                 const int* __restrict__ flag) {
  constexpr int LDK = 136;  // 128 + 8 pad
  __shared__ short a_lds[64 * LDK];
  __shared__ short b_lds[64 * LDK];
  __shared__ float lds_al[128];  // [0:64)=al_s rows, [64:128)=al_d rows
  int nrt = (M + 63) / 64;
  int bid = blockIdx.x;
  int xcd = bid & 7;
  int jj = bid >> 3;
  int col_t = jj & 3;
  int row_t = (jj >> 2) * 8 + xcd;
  if (row_t >= nrt) return;
  int isbf = A_DUAL ? *flag : 1;
  int tid = threadIdx.x;
  int row0 = row_t * 64;
  int col0 = col_t * 64;
  int lane = tid & 63;
  int wv = tid >> 6;
  int wm = (wv & 1) * 32, wn = (wv >> 1) * 32;
  int l15 = lane & 15, quad = lane >> 4;
  if (tid < 128) lds_al[tid] = 0.f;
  f32x4 acc00 = {0.f, 0.f, 0.f, 0.f}, acc01 = acc00, acc10 = acc00, acc11 = acc00;

  for (int kb = 0; kb < K; kb += 128) {
    if (kb) __syncthreads();
    for (int idx = tid; idx < 64 * 16; idx += 256) {
      int r = idx >> 4, sidx = idx & 15;
      int gr = row0 + r;
      size_t gi = (size_t)gr * K + kb + sidx * 8;
      uint4 av = make_uint4(0u, 0u, 0u, 0u);
      if (A_DUAL && !isbf) {
        if (gr < M) {
          float4 f0 = ((const float4*)Ap)[gi / 4];
          float4 f1 = ((const float4*)Ap)[gi / 4 + 1];
          union { uint4 v; bf16 h[8]; } o;
          o.h[0] = __float2bfloat16(f0.x);
          o.h[1] = __float2bfloat16(f0.y);
          o.h[2] = __float2bfloat16(f0.z);
          o.h[3] = __float2bfloat16(f0.w);
          o.h[4] = __float2bfloat16(f1.x);
          o.h[5] = __float2bfloat16(f1.y);
          o.h[6] = __float2bfloat16(f1.z);
          o.h[7] = __float2bfloat16(f1.w);
          av = o.v;
        }
      } else {
        if (gr < M) av = *(const uint4*)&((const bf16*)Ap)[gi];
      }
      *(uint4*)&a_lds[r * LDK + sidx * 8] = av;
      *(uint4*)&b_lds[r * LDK + sidx * 8] =
          *(const uint4*)&Bt[(size_t)(col0 + r) * K + kb + sidx * 8];
    }
    __syncthreads();
#pragma unroll
    for (int k0 = 0; k0 < 128; k0 += 32) {
      int ko = k0 + quad * 8;
      short8 a0 = *(const short8*)&a_lds[(wm + l15) * LDK + ko];
      short8 a1 = *(const short8*)&a_lds[(wm + 16 + l15) * LDK + ko];
      short8 b0 = *(const short8*)&b_lds[(wn + l15) * LDK + ko];
      short8 b1 = *(const short8*)&b_lds[(wn + 16 + l15) * LDK + ko];
      acc00 = __builtin_amdgcn_mfma_f32_16x16x32_bf16(a0, b0, acc00, 0, 0, 0);
      acc01 = __builtin_amdgcn_mfma_f32_16x16x32_bf16(a0, b1, acc01, 0, 0, 0);
      acc10 = __builtin_amdgcn_mfma_f32_16x16x32_bf16(a1, b0, acc10, 0, 0, 0);
      acc11 = __builtin_amdgcn_mfma_f32_16x16x32_bf16(a1, b1, acc11, 0, 0, 0);
    }
  }
  const f32x4* accs[2][2] = {{&acc00, &acc01}, {&acc10, &acc11}};
  float as0 = a_sf[col0 + wn + l15], as1 = a_sf[col0 + wn + 16 + l15];
  float ad0 = a_df[col0 + wn + l15], ad1 = a_df[col0 + wn + 16 + l15];
#pragma unroll
  for (int i = 0; i < 2; i++) {
    float sp[4], dp[4];
#pragma unroll
    for (int r = 0; r < 4; r++) {
      float v0 = (*accs[i][0])[r], v1 = (*accs[i][1])[r];
      sp[r] = v0 * as0 + v1 * as1;
      dp[r] = v0 * ad0 + v1 * ad1;
      int grow = row0 + wm + i * 16 + quad * 4 + r;
      if (grow < M) {
        C[(size_t)grow * 256 + col0 + wn + l15] = __float2bfloat16(v0);
        C[(size_t)grow * 256 + col0 + wn + 16 + l15] = __float2bfloat16(v1);
      }
    }
#pragma unroll
    for (int off = 1; off < 16; off <<= 1) {
#pragma unroll
      for (int r = 0; r < 4; r++) {
        sp[r] += __shfl_xor(sp[r], off);
        dp[r] += __shfl_xor(dp[r], off);
      }
    }
    if (l15 == 0) {
#pragma unroll
      for (int r = 0; r < 4; r++) {
        int lrow = wm + i * 16 + quad * 4 + r;
        atomicAdd(&lds_al[lrow], sp[r]);
        atomicAdd(&lds_al[64 + lrow], dp[r]);
      }
    }
  }
  __syncthreads();
  if (tid < 64 && row0 + tid < M) {
    int row = row0 + tid;
    *(float*)(blob + (size_t)row * 128 + 64 + (size_t)col_t * 4) = lds_al[tid];
    al_d[(size_t)row * 4 + col_t] = lds_al[64 + tid];
  }
}

// ---------------- fused attention + aggregation: wave per node.
// Quarter-waves (16 lanes) process slots rowptr[n]+q, step 4; 1-deep
// software pipeline (csr 2 slots ahead, data 1 slot ahead), exec-guarded
// loads. Per-edge side data (pe row + al_s) comes from one 128B blob
// record -> single random line + the 512B xp row. Plain stores (NT
// measured -2.5us/dispatch worse).
template <bool RELU, bool OUT_DUAL>
__global__ __launch_bounds__(256) void agg_kernel(const bf16* __restrict__ xp,
                                                  const char* __restrict__ blob,
                                                  const float* __restrict__ al_d,
                                                  const float* __restrict__ w_pe,
                                                  const int* __restrict__ csr_src,
                                                  const int* __restrict__ rowptr,
                                                  void* out, const int* __restrict__ flag) {
  int isbf = OUT_DUAL ? *flag : 1;
  int lane = threadIdx.x & 63;
  int n = blockIdx.x * 4 + (threadIdx.x >> 6);
  int q = lane >> 4, li = lane & 15, h = li >> 2;
  const char* bn = blob + (size_t)n * 128;
  unsigned int ud = *(const unsigned int*)(bn + li * 4);
  float pdlo = __uint_as_float(ud << 16);
  float pdhi = __uint_as_float(ud & 0xffff0000u);
  float ald = al_d[(size_t)n * 4 + h];
  float wph = w_pe[h];
  int s1 = rowptr[n + 1];
  int s = rowptr[n] + q;
  f32x2 acc2[8];
#pragma unroll
  for (int j = 0; j < 8; j++) acc2[j] = (f32x2){0.f, 0.f};
  float asum = 0.f;

  int sn_c = -1, sn_n = -1;
  unsigned int pes_c = 0, pes_n = 0;
  float als_c = 0.f, als_n = 0.f;
  uint4 z = make_uint4(0u, 0u, 0u, 0u);
  uint4 xc0 = z, xc1 = z, xn0 = z, xn1 = z;
  if (s < s1) {
    sn_c = csr_src[s];
    const char* bs = blob + (size_t)sn_c * 128;
    pes_c = *(const unsigned int*)(bs + li * 4);
    als_c = *(const float*)(bs + 64 + h * 4);
    const uint4* b = (const uint4*)&xp[(size_t)sn_c * 256 + li * 16];
    xc0 = b[0];
    xc1 = b[1];
    if (s + 4 < s1) sn_n = csr_src[s + 4];
  }
  int sf = s + 8;
  while (sn_c >= 0) {
    if (sn_n >= 0) {
      const char* bs = blob + (size_t)sn_n * 128;
      pes_n = *(const unsigned int*)(bs + li * 4);
      als_n = *(const float*)(bs + 64 + h * 4);
      const uint4* b = (const uint4*)&xp[(size_t)sn_n * 256 + li * 16];
      xn0 = b[0];
      xn1 = b[1];
    }
    int sn_f = (sf < s1) ? csr_src[sf] : -1;
    sf += 4;
    float dx = __uint_as_float(pes_c << 16) - pdlo;
    float dy = __uint_as_float(pes_c & 0xffff0000u) - pdhi;
    float d2 = dx * dx + dy * dy;
#pragma unroll
    for (int off = 1; off < 16; off <<= 1) d2 += __shfl_xor(d2, off);
    float lg = als_c + ald;
    lg = fmaxf(lg, 0.f) + NEG_SLOPE * fminf(lg, 0.f);
    lg += __builtin_amdgcn_sqrtf(d2 + 1e-8f) * wph;
    float a = __expf(lg);
    f32x2 av = {a, a};
    unsigned int u[8] = {xc0.x, xc0.y, xc0.z, xc0.w, xc1.x, xc1.y, xc1.z, xc1.w};
#pragma unroll
    for (int p = 0; p < 8; p++) {
      f32x2 xv;
      xv.x = __uint_as_float(u[p] << 16);
      xv.y = __uint_as_float(u[p] & 0xffff0000u);
      acc2[p] += av * xv;
    }
    asum += a;
    sn_c = sn_n;
    pes_c = pes_n;
    als_c = als_n;
    xc0 = xn0;
    xc1 = xn1;
    sn_n = sn_f;
  }
#pragma unroll
  for (int j = 0; j < 8; j++) {
    acc2[j].x += __shfl_xor(acc2[j].x, 16);
    acc2[j].x += __shfl_xor(acc2[j].x, 32);
    acc2[j].y += __shfl_xor(acc2[j].y, 16);
    acc2[j].y += __shfl_xor(acc2[j].y, 32);
  }
  asum += __shfl_xor(asum, 16);
  asum += __shfl_xor(asum, 32);
  if (q == 0) {
    float inv = 1.f / (asum + 1e-16f);
    size_t oi = (size_t)n * 256 + li * 16;
    if (OUT_DUAL && !isbf) {
      float* of = (float*)out;
#pragma unroll
      for (int p = 0; p < 4; p++) {
        float4 f;
        f.x = acc2[2 * p].x * inv;
        f.y = acc2[2 * p].y * inv;
        f.z = acc2[2 * p + 1].x * inv;
        f.w = acc2[2 * p + 1].y * inv;
        if (RELU) {
          f.x = fmaxf(f.x, 0.f);
          f.y = fmaxf(f.y, 0.f);
          f.z = fmaxf(f.z, 0.f);
          f.w = fmaxf(f.w, 0.f);
        }
        *(float4*)&of[oi + 4 * p] = f;
      }
    } else {
      union { uint4 v[2]; bf16 hh[16]; } o;
#pragma unroll
      for (int j = 0; j < 8; j++) {
        float rlo = acc2[j].x * inv;
        float rhi = acc2[j].y * inv;
        if (RELU) {
          rlo = fmaxf(rlo, 0.f);
          rhi = fmaxf(rhi, 0.f);
        }
        o.hh[2 * j] = __float2bfloat16(rlo);
        o.hh[2 * j + 1] = __float2bfloat16(rhi);
      }
      uint4* ob = (uint4*)&((bf16*)out)[oi];
      ob[0] = o.v[0];
      ob[1] = o.v[1];
    }
  }
}

extern "C" void kernel_launch(void* const* d_in, const int* in_sizes, int n_in,
                              void* d_out, int out_size, void* d_ws, size_t ws_size,
                              hipStream_t stream) {
  const void* x_masked = d_in[1];
  const void* PE = d_in[2];
  const void* PE_noise = d_in[3];
  const int* ei = (const int*)d_in[4];
  const int* src = ei;
  const int* dst = ei + N_EDGES;

  char* w = (char*)d_ws;
  auto alloc = [&](size_t bytes) -> char* {
    char* p = w;
    w += (bytes + 255) / 256 * 256;
    return p;
  };
  int* flag = (int*)alloc(4);
  float* W_peg_f = (float*)alloc(1024 * 4);
  float* b_peg_f = (float*)alloc(32 * 4);
  float* a_s0_f = (float*)alloc(256 * 4);
  float* a_d0_f = (float*)alloc(256 * 4);
  float* w_pe0_f = (float*)alloc(4 * 4);
  float* W_u0_f = (float*)alloc(1024 * 4);
  float* a_s1_f = (float*)alloc(256 * 4);
  float* a_d1_f = (float*)alloc(256 * 4);
  float* w_pe1_f = (float*)alloc(4 * 4);
  float* W_u1_f = (float*)alloc(1024 * 4);
  bf16* Wt0 = (bf16*)alloc(32768 * 2);
  bf16* Wt1 = (bf16*)alloc(65536 * 2);
  char* blob0 = alloc((size_t)N_NODES * 128);  // pe0 + al_s(layer0)
  char* blob1 = alloc((size_t)N_NODES * 128);  // pe1 + al_s(layer1)
  float* al_d = (float*)alloc((size_t)N_NODES * 4 * 4);
  int* degfill = (int*)alloc(((size_t)N_NODES * 2 + 64) * 4);  // deg|fill|scanflags
  int* deg = degfill;
  int* fill = degfill + N_NODES;
  int* sflags = degfill + 2 * N_NODES;
  int* rowptr = (int*)alloc((size_t)(N_NODES + 1) * 4);
  int* bsum = (int*)alloc(64 * 4);
  int* csr_src = (int*)alloc((size_t)N_EDGES * 4);
  bf16* xp = (bf16*)alloc((size_t)N_NODES * 256 * 2);
  bf16* hm0 = (bf16*)alloc((size_t)N_NODES * 256 * 2);

  CvtJobs jobs;
  int ji = 0;
  auto addjob = [&](const void* s, float* d, int n) {
    jobs.src[ji] = s; jobs.dst[ji] = d; jobs.n[ji] = n; ji++;
  };
  addjob(d_in[5], W_peg_f, 1024);
  addjob(d_in[6], b_peg_f, 32);
  addjob(d_in[8], a_s0_f, 256);
  addjob(d_in[9], a_d0_f, 256);
  addjob(d_in[10], w_pe0_f, 4);
  addjob(d_in[11], W_u0_f, 1024);
  addjob(d_in[13], a_s1_f, 256);
  addjob(d_in[14], a_d1_f, 256);
  addjob(d_in[15], w_pe1_f, 4);
  addjob(d_in[16], W_u1_f, 1024);

  // zero deg/fill/scan-flags before prep's histogram atomics
  hipMemsetAsync(degfill, 0, ((size_t)N_NODES * 2 + 64) * 4, stream);

  // prep (detect+cvt+transposes, blocks 0-399) + histogram (blocks 400+)
  prep_kernel<<<400 + NCHUNK, 256, 0, stream>>>(
      jobs, (const unsigned short*)d_in[5], d_in[7], Wt0, d_in[12], Wt1, flag,
      dst, deg);

  // single-dispatch scan (deg -> rowptr)
  scan_kernel<<<49, 1024, 0, stream>>>(deg, rowptr, bsum, sflags, N_NODES);

  // XCD-partitioned CSR fill (25000) + PEG chains (12500)
  fill_peg_kernel<<<NFILL8 + 2 * NDIV8, 256, 0, stream>>>(
      src, dst, rowptr, fill, csr_src, PE_noise, PE, W_peg_f, b_peg_f, W_u0_f,
      W_u1_f, d_out, (size_t)N_NODES * 256, blob0, blob1, flag);

  // XCD-grouped 1D grid: ceil(nrt/8)*8 row-tiles * 4 col-tiles
  int nrt = (N_NODES + 63) / 64;
  int gblk = ((nrt + 7) / 8) * 8 * 4;

  // ---- GAT layer 0 (A = x_masked dual, K=128); al fused into gemm epilogue
  mfma_gemm<128, true><<<gblk, 256, 0, stream>>>(x_masked, Wt0, xp, N_NODES,
                                                 a_s0_f, a_d0_f, blob0, al_d, flag);
  agg_kernel<true, false><<<N_NODES / 4, 256, 0, stream>>>(
      xp, blob0, al_d, w_pe0_f, csr_src, rowptr, hm0, flag);

  // ---- GAT layer 1 (A = hm0 bf16, K=256)
  mfma_gemm<256, false><<<gblk, 256, 0, stream>>>(hm0, Wt1, xp, N_NODES,
                                                  a_s1_f, a_d1_f, blob1, al_d, flag);
  agg_kernel<false, true><<<N_NODES / 4, 256, 0, stream>>>(
      xp, blob1, al_d, w_pe1_f, csr_src, rowptr, d_out, flag);
}

// Round 9
// 408.546 us; speedup vs baseline: 1.1099x; 1.1099x over previous
//
#include <hip/hip_runtime.h>
#include <hip/hip_bf16.h>

#define N_NODES 50000
#define N_EDGES 800000
#define NEG_SLOPE 0.2f

typedef __hip_bfloat16 bf16;
typedef __attribute__((ext_vector_type(8))) short short8;
typedef __attribute__((ext_vector_type(4))) float f32x4;
typedef __attribute__((ext_vector_type(2))) float f32x2;

__device__ __forceinline__ float b2f(bf16 x) { return __bfloat162float(x); }

// flag: 1 = float tensors in d_in/d_out are bf16; 0 = fp32.
__device__ __forceinline__ float ldsel(const void* p, size_t i, int isbf) {
  return isbf ? __bfloat162float(((const bf16*)p)[i]) : ((const float*)p)[i];
}
__device__ __forceinline__ void stsel(void* p, size_t i, int isbf, float v) {
  if (isbf) ((bf16*)p)[i] = __float2bfloat16(v);
  else ((float*)p)[i] = v;
}

// per-block dtype detection (256 threads sample 256 even shorts of W_peg)
__device__ __forceinline__ int block_detect(const unsigned short* __restrict__ probe) {
  __shared__ int wcount;
  int tid = threadIdx.x;
  if (tid == 0) wcount = 0;
  __syncthreads();
  int ex = (probe[2 * tid] >> 7) & 0xFF;
  unsigned long long m = __ballot(ex >= 0x85);
  if ((tid & 63) == 0) atomicAdd(&wcount, __popcll(m));
  __syncthreads();
  return wcount < 8;
}

// ---------------- merged prep: dtype flag + 10 small cvts + 2 weight
// transposes + edge histogram (blocks >= 400). The histogram's atomicAdd
// return value IS the edge's slot within its dst row -> persist to epos[]
// so the fill pass needs no second atomic.
struct CvtJobs {
  const void* src[10];
  float* dst[10];
  int n[10];
};
__global__ __launch_bounds__(256) void prep_kernel(CvtJobs jobs,
                                                   const unsigned short* __restrict__ probe,
                                                   const void* __restrict__ W0in,
                                                   bf16* __restrict__ Wt0,
                                                   const void* __restrict__ W1in,
                                                   bf16* __restrict__ Wt1,
                                                   int* __restrict__ flag,
                                                   const int* __restrict__ dst,
                                                   int* __restrict__ deg,
                                                   int* __restrict__ epos) {
  int tid = threadIdx.x;
  int b = blockIdx.x;
  if (b >= 400) {  // histogram part
    int e = (b - 400) * 256 + tid;
    epos[e] = atomicAdd(&deg[dst[e]], 1);
    return;
  }
  int isbf = block_detect(probe);
  if (b == 0 && tid == 0) *flag = isbf;
  if (b < 16) {
    for (int j = 0; j < 10; j++) {
      int n = jobs.n[j];
      const void* s = jobs.src[j];
      float* d = jobs.dst[j];
      for (int i = b * 256 + tid; i < n; i += 16 * 256) d[i] = ldsel(s, i, isbf);
    }
  } else if (b < 16 + 128) {
    int i = (b - 16) * 256 + tid;  // [0, 32768): Wt0 [256][128]
    int n = i >> 7, k = i & 127;
    Wt0[i] = __float2bfloat16(ldsel(W0in, (size_t)k * 256 + n, isbf));
  } else {
    int i = (b - 144) * 256 + tid;  // [0, 65536): Wt1 [256][256]
    int n = i >> 8, k = i & 255;
    Wt1[i] = __float2bfloat16(ldsel(W1in, (size_t)k * 256 + n, isbf));
  }
}

// ---------------- CSR scan (two dispatches; measured faster than the
// single-dispatch spin-scan, whose serialized finalize cost ~10-15us)
__global__ __launch_bounds__(1024) void scan1_kernel(const int* __restrict__ deg,
                                                     int* __restrict__ tmp,
                                                     int* __restrict__ bsum, int n) {
  __shared__ int wsum[16];
  int tid = threadIdx.x;
  int idx = blockIdx.x * 1024 + tid;
  int v = (idx < n) ? deg[idx] : 0;
  int incl = v;
#pragma unroll
  for (int off = 1; off < 64; off <<= 1) {
    int t = __shfl_up(incl, off);
    if ((tid & 63) >= off) incl += t;
  }
  int wid = tid >> 6;
  if ((tid & 63) == 63) wsum[wid] = incl;
  __syncthreads();
  if (tid == 0) {
    int acc = 0;
#pragma unroll
    for (int w = 0; w < 16; w++) {
      int t = wsum[w];
      wsum[w] = acc;
      acc += t;
    }
    bsum[blockIdx.x] = acc;
  }
  __syncthreads();
  if (idx < n) tmp[idx] = wsum[wid] + incl;
}

__global__ __launch_bounds__(1024) void scan3_kernel(const int* __restrict__ tmp,
                                                     const int* __restrict__ bsum,
                                                     int* __restrict__ rowptr, int n,
                                                     int nb) {
  __shared__ int lb[64];
  int tid = threadIdx.x;
  if (tid < nb) lb[tid] = bsum[tid];
  __syncthreads();
  int pre = 0;
  for (int j = 0; j < blockIdx.x; j++) pre += lb[j];
  int idx = blockIdx.x * 1024 + tid;
  if (idx < n) rowptr[idx + 1] = tmp[idx] + pre;
  if (idx == 0) rowptr[0] = 0;
}

// ---------------- merged CSR-fill + PEG chains.
// blocks [0, 25000): XCD-partitioned CSR fill, ATOMIC-FREE (slot index
// precomputed in prep). Block b covers edge chunk b>>3, commits only dst
// in XCD (b&7)'s node range so csr line writes merge in one L2.
// blocks [25000, 25000+12500): PEG chains, 8 nodes/block.
#define NCHUNK (N_EDGES / 256)   // 3125
#define NFILL8 (NCHUNK * 8)      // 25000
#define NDIV8 (N_NODES / 8)      // 6250
__global__ __launch_bounds__(256) void fill_peg_kernel(const int* __restrict__ src,
                                                       const int* __restrict__ dst,
                                                       const int* __restrict__ rowptr,
                                                       const int* __restrict__ epos,
                                                       int* __restrict__ csr_src,
                                                       const void* __restrict__ pen,
                                                       const void* __restrict__ pem,
                                                       const float* __restrict__ Wpeg,
                                                       const float* __restrict__ bpeg,
                                                       const float* __restrict__ Wu0,
                                                       const float* __restrict__ Wu1,
                                                       void* out, size_t out_off,
                                                       char* __restrict__ blob0,
                                                       char* __restrict__ blob1,
                                                       const int* __restrict__ flag) {
  __shared__ float w1[1024], w2[1024], w3[1024];
  __shared__ float rowA[256], rowB[256];
  int tid = threadIdx.x;
  int b = blockIdx.x;
  if (b < NFILL8) {  // XCD-partitioned atomic-free CSR fill
    int xcd = b & 7;
    int e = (b >> 3) * 256 + tid;
    int d = dst[e];
    int lo = xcd * NDIV8;
    if (d >= lo && d < lo + NDIV8) {
      csr_src[rowptr[d] + epos[e]] = src[e];
    }
    return;
  }
  int pb = b - NFILL8;
  int isbf = *flag;
  bool c3 = pb < NDIV8;
  int n0 = (c3 ? pb : pb - NDIV8) * 8;
  const void* in = c3 ? pen : pem;
  for (int i = tid; i < 1024; i += 256) {
    w1[i] = Wpeg[i];
    w2[i] = Wu0[i];
    if (c3) w3[i] = Wu1[i];
  }
  rowA[tid] = ldsel(in, (size_t)n0 * 32 + tid, isbf);
  __syncthreads();
  int col = tid & 31, ln = tid >> 5;
  size_t bi = ((size_t)(n0 + ln)) * 64 + col;  // bf16 index, stride 64 (=128B)
  float acc = bpeg[col];
#pragma unroll
  for (int j = 0; j < 32; j++) acc += rowA[ln * 32 + j] * w1[j * 32 + col];
  acc = fmaxf(acc, 0.f);
  if (!c3) ((bf16*)blob0)[bi] = __float2bfloat16(acc);
  rowB[tid] = acc;
  __syncthreads();
  acc = 0.f;
#pragma unroll
  for (int j = 0; j < 32; j++) acc += rowB[ln * 32 + j] * w2[j * 32 + col];
  acc = fmaxf(acc, 0.f);
  if (!c3) {
    ((bf16*)blob1)[bi] = __float2bfloat16(acc);
    return;
  }
  rowA[tid] = acc;
  __syncthreads();
  acc = 0.f;
#pragma unroll
  for (int j = 0; j < 32; j++) acc += rowA[ln * 32 + j] * w3[j * 32 + col];
  stsel(out, out_off + (size_t)n0 * 32 + tid, isbf, fmaxf(acc, 0.f));
}

// ---------------- MFMA feature GEMM + fused al_s/al_d epilogue.
// C[M,256] = A[M,K] @ B[K,256]; BK=128 / LDK=136 (conflict-free, measured).
// XCD-grouped tile remap: 4 col-tiles of a row tile on the same XCD.
// al_s -> blob [64,80) of the 128B node record; al_d -> its own array.
template <int K, bool A_DUAL>
__global__ __launch_bounds__(256) void mfma_gemm(const void* __restrict__ Ap,
                                                 const bf16* __restrict__ Bt,
                                                 bf16* __restrict__ C, int M,
                                                 const float* __restrict__ a_sf,
                                                 const float* __restrict__ a_df,
                                                 char* __restrict__ blob,
                                                 float* __restrict__ al_d,
                                                 const int* __restrict__ flag) {
  constexpr int LDK = 136;  // 128 + 8 pad
  __shared__ short a_lds[64 * LDK];
  __shared__ short b_lds[64 * LDK];
  __shared__ float lds_al[128];  // [0:64)=al_s rows, [64:128)=al_d rows
  int nrt = (M + 63) / 64;
  int bid = blockIdx.x;
  int xcd = bid & 7;
  int jj = bid >> 3;
  int col_t = jj & 3;
  int row_t = (jj >> 2) * 8 + xcd;
  if (row_t >= nrt) return;
  int isbf = A_DUAL ? *flag : 1;
  int tid = threadIdx.x;
  int row0 = row_t * 64;
  int col0 = col_t * 64;
  int lane = tid & 63;
  int wv = tid >> 6;
  int wm = (wv & 1) * 32, wn = (wv >> 1) * 32;
  int l15 = lane & 15, quad = lane >> 4;
  if (tid < 128) lds_al[tid] = 0.f;
  f32x4 acc00 = {0.f, 0.f, 0.f, 0.f}, acc01 = acc00, acc10 = acc00, acc11 = acc00;

  for (int kb = 0; kb < K; kb += 128) {
    if (kb) __syncthreads();
    for (int idx = tid; idx < 64 * 16; idx += 256) {
      int r = idx >> 4, sidx = idx & 15;
      int gr = row0 + r;
      size_t gi = (size_t)gr * K + kb + sidx * 8;
      uint4 av = make_uint4(0u, 0u, 0u, 0u);
      if (A_DUAL && !isbf) {
        if (gr < M) {
          float4 f0 = ((const float4*)Ap)[gi / 4];
          float4 f1 = ((const float4*)Ap)[gi / 4 + 1];
          union { uint4 v; bf16 h[8]; } o;
          o.h[0] = __float2bfloat16(f0.x);
          o.h[1] = __float2bfloat16(f0.y);
          o.h[2] = __float2bfloat16(f0.z);
          o.h[3] = __float2bfloat16(f0.w);
          o.h[4] = __float2bfloat16(f1.x);
          o.h[5] = __float2bfloat16(f1.y);
          o.h[6] = __float2bfloat16(f1.z);
          o.h[7] = __float2bfloat16(f1.w);
          av = o.v;
        }
      } else {
        if (gr < M) av = *(const uint4*)&((const bf16*)Ap)[gi];
      }
      *(uint4*)&a_lds[r * LDK + sidx * 8] = av;
      *(uint4*)&b_lds[r * LDK + sidx * 8] =
          *(const uint4*)&Bt[(size_t)(col0 + r) * K + kb + sidx * 8];
    }
    __syncthreads();
#pragma unroll
    for (int k0 = 0; k0 < 128; k0 += 32) {
      int ko = k0 + quad * 8;
      short8 a0 = *(const short8*)&a_lds[(wm + l15) * LDK + ko];
      short8 a1 = *(const short8*)&a_lds[(wm + 16 + l15) * LDK + ko];
      short8 b0 = *(const short8*)&b_lds[(wn + l15) * LDK + ko];
      short8 b1 = *(const short8*)&b_lds[(wn + 16 + l15) * LDK + ko];
      acc00 = __builtin_amdgcn_mfma_f32_16x16x32_bf16(a0, b0, acc00, 0, 0, 0);
      acc01 = __builtin_amdgcn_mfma_f32_16x16x32_bf16(a0, b1, acc01, 0, 0, 0);
      acc10 = __builtin_amdgcn_mfma_f32_16x16x32_bf16(a1, b0, acc10, 0, 0, 0);
      acc11 = __builtin_amdgcn_mfma_f32_16x16x32_bf16(a1, b1, acc11, 0, 0, 0);
    }
  }
  const f32x4* accs[2][2] = {{&acc00, &acc01}, {&acc10, &acc11}};
  float as0 = a_sf[col0 + wn + l15], as1 = a_sf[col0 + wn + 16 + l15];
  float ad0 = a_df[col0 + wn + l15], ad1 = a_df[col0 + wn + 16 + l15];
#pragma unroll
  for (int i = 0; i < 2; i++) {
    float sp[4], dp[4];
#pragma unroll
    for (int r = 0; r < 4; r++) {
      float v0 = (*accs[i][0])[r], v1 = (*accs[i][1])[r];
      sp[r] = v0 * as0 + v1 * as1;
      dp[r] = v0 * ad0 + v1 * ad1;
      int grow = row0 + wm + i * 16 + quad * 4 + r;
      if (grow < M) {
        C[(size_t)grow * 256 + col0 + wn + l15] = __float2bfloat16(v0);
        C[(size_t)grow * 256 + col0 + wn + 16 + l15] = __float2bfloat16(v1);
      }
    }
#pragma unroll
    for (int off = 1; off < 16; off <<= 1) {
#pragma unroll
      for (int r = 0; r < 4; r++) {
        sp[r] += __shfl_xor(sp[r], off);
        dp[r] += __shfl_xor(dp[r], off);
      }
    }
    if (l15 == 0) {
#pragma unroll
      for (int r = 0; r < 4; r++) {
        int lrow = wm + i * 16 + quad * 4 + r;
        atomicAdd(&lds_al[lrow], sp[r]);
        atomicAdd(&lds_al[64 + lrow], dp[r]);
      }
    }
  }
  __syncthreads();
  if (tid < 64 && row0 + tid < M) {
    int row = row0 + tid;
    *(float*)(blob + (size_t)row * 128 + 64 + (size_t)col_t * 4) = lds_al[tid];
    al_d[(size_t)row * 4 + col_t] = lds_al[64 + tid];
  }
}

// ---------------- fused attention + aggregation: wave per node.
// Quarter-waves (16 lanes) process slots rowptr[n]+q, step 4; 1-deep
// software pipeline (csr 2 slots ahead, data 1 slot ahead), exec-guarded
// loads. Per-edge side data (pe row + al_s) comes from one 128B blob
// record -> single random line + the 512B xp row. Plain stores.
// Five implementations all pin at ~3.9-4.0 TB/s effective: the random
// 512B-gather fabric ceiling. This kernel is at its roofline.
template <bool RELU, bool OUT_DUAL>
__global__ __launch_bounds__(256) void agg_kernel(const bf16* __restrict__ xp,
                                                  const char* __restrict__ blob,
                                                  const float* __restrict__ al_d,
                                                  const float* __restrict__ w_pe,
                                                  const int* __restrict__ csr_src,
                                                  const int* __restrict__ rowptr,
                                                  void* out, const int* __restrict__ flag) {
  int isbf = OUT_DUAL ? *flag : 1;
  int lane = threadIdx.x & 63;
  int n = blockIdx.x * 4 + (threadIdx.x >> 6);
  int q = lane >> 4, li = lane & 15, h = li >> 2;
  const char* bn = blob + (size_t)n * 128;
  unsigned int ud = *(const unsigned int*)(bn + li * 4);
  float pdlo = __uint_as_float(ud << 16);
  float pdhi = __uint_as_float(ud & 0xffff0000u);
  float ald = al_d[(size_t)n * 4 + h];
  float wph = w_pe[h];
  int s1 = rowptr[n + 1];
  int s = rowptr[n] + q;
  f32x2 acc2[8];
#pragma unroll
  for (int j = 0; j < 8; j++) acc2[j] = (f32x2){0.f, 0.f};
  float asum = 0.f;

  int sn_c = -1, sn_n = -1;
  unsigned int pes_c = 0, pes_n = 0;
  float als_c = 0.f, als_n = 0.f;
  uint4 z = make_uint4(0u, 0u, 0u, 0u);
  uint4 xc0 = z, xc1 = z, xn0 = z, xn1 = z;
  if (s < s1) {
    sn_c = csr_src[s];
    const char* bs = blob + (size_t)sn_c * 128;
    pes_c = *(const unsigned int*)(bs + li * 4);
    als_c = *(const float*)(bs + 64 + h * 4);
    const uint4* b = (const uint4*)&xp[(size_t)sn_c * 256 + li * 16];
    xc0 = b[0];
    xc1 = b[1];
    if (s + 4 < s1) sn_n = csr_src[s + 4];
  }
  int sf = s + 8;
  while (sn_c >= 0) {
    if (sn_n >= 0) {
      const char* bs = blob + (size_t)sn_n * 128;
      pes_n = *(const unsigned int*)(bs + li * 4);
      als_n = *(const float*)(bs + 64 + h * 4);
      const uint4* b = (const uint4*)&xp[(size_t)sn_n * 256 + li * 16];
      xn0 = b[0];
      xn1 = b[1];
    }
    int sn_f = (sf < s1) ? csr_src[sf] : -1;
    sf += 4;
    float dx = __uint_as_float(pes_c << 16) - pdlo;
    float dy = __uint_as_float(pes_c & 0xffff0000u) - pdhi;
    float d2 = dx * dx + dy * dy;
#pragma unroll
    for (int off = 1; off < 16; off <<= 1) d2 += __shfl_xor(d2, off);
    float lg = als_c + ald;
    lg = fmaxf(lg, 0.f) + NEG_SLOPE * fminf(lg, 0.f);
    lg += __builtin_amdgcn_sqrtf(d2 + 1e-8f) * wph;
    float a = __expf(lg);
    f32x2 av = {a, a};
    unsigned int u[8] = {xc0.x, xc0.y, xc0.z, xc0.w, xc1.x, xc1.y, xc1.z, xc1.w};
#pragma unroll
    for (int p = 0; p < 8; p++) {
      f32x2 xv;
      xv.x = __uint_as_float(u[p] << 16);
      xv.y = __uint_as_float(u[p] & 0xffff0000u);
      acc2[p] += av * xv;
    }
    asum += a;
    sn_c = sn_n;
    pes_c = pes_n;
    als_c = als_n;
    xc0 = xn0;
    xc1 = xn1;
    sn_n = sn_f;
  }
#pragma unroll
  for (int j = 0; j < 8; j++) {
    acc2[j].x += __shfl_xor(acc2[j].x, 16);
    acc2[j].x += __shfl_xor(acc2[j].x, 32);
    acc2[j].y += __shfl_xor(acc2[j].y, 16);
    acc2[j].y += __shfl_xor(acc2[j].y, 32);
  }
  asum += __shfl_xor(asum, 16);
  asum += __shfl_xor(asum, 32);
  if (q == 0) {
    float inv = 1.f / (asum + 1e-16f);
    size_t oi = (size_t)n * 256 + li * 16;
    if (OUT_DUAL && !isbf) {
      float* of = (float*)out;
#pragma unroll
      for (int p = 0; p < 4; p++) {
        float4 f;
        f.x = acc2[2 * p].x * inv;
        f.y = acc2[2 * p].y * inv;
        f.z = acc2[2 * p + 1].x * inv;
        f.w = acc2[2 * p + 1].y * inv;
        if (RELU) {
          f.x = fmaxf(f.x, 0.f);
          f.y = fmaxf(f.y, 0.f);
          f.z = fmaxf(f.z, 0.f);
          f.w = fmaxf(f.w, 0.f);
        }
        *(float4*)&of[oi + 4 * p] = f;
      }
    } else {
      union { uint4 v[2]; bf16 hh[16]; } o;
#pragma unroll
      for (int j = 0; j < 8; j++) {
        float rlo = acc2[j].x * inv;
        float rhi = acc2[j].y * inv;
        if (RELU) {
          rlo = fmaxf(rlo, 0.f);
          rhi = fmaxf(rhi, 0.f);
        }
        o.hh[2 * j] = __float2bfloat16(rlo);
        o.hh[2 * j + 1] = __float2bfloat16(rhi);
      }
      uint4* ob = (uint4*)&((bf16*)out)[oi];
      ob[0] = o.v[0];
      ob[1] = o.v[1];
    }
  }
}

extern "C" void kernel_launch(void* const* d_in, const int* in_sizes, int n_in,
                              void* d_out, int out_size, void* d_ws, size_t ws_size,
                              hipStream_t stream) {
  const void* x_masked = d_in[1];
  const void* PE = d_in[2];
  const void* PE_noise = d_in[3];
  const int* ei = (const int*)d_in[4];
  const int* src = ei;
  const int* dst = ei + N_EDGES;

  char* w = (char*)d_ws;
  auto alloc = [&](size_t bytes) -> char* {
    char* p = w;
    w += (bytes + 255) / 256 * 256;
    return p;
  };
  int* flag = (int*)alloc(4);
  float* W_peg_f = (float*)alloc(1024 * 4);
  float* b_peg_f = (float*)alloc(32 * 4);
  float* a_s0_f = (float*)alloc(256 * 4);
  float* a_d0_f = (float*)alloc(256 * 4);
  float* w_pe0_f = (float*)alloc(4 * 4);
  float* W_u0_f = (float*)alloc(1024 * 4);
  float* a_s1_f = (float*)alloc(256 * 4);
  float* a_d1_f = (float*)alloc(256 * 4);
  float* w_pe1_f = (float*)alloc(4 * 4);
  float* W_u1_f = (float*)alloc(1024 * 4);
  bf16* Wt0 = (bf16*)alloc(32768 * 2);
  bf16* Wt1 = (bf16*)alloc(65536 * 2);
  char* blob0 = alloc((size_t)N_NODES * 128);  // pe0 + al_s(layer0)
  char* blob1 = alloc((size_t)N_NODES * 128);  // pe1 + al_s(layer1)
  float* al_d = (float*)alloc((size_t)N_NODES * 4 * 4);
  int* deg = (int*)alloc((size_t)N_NODES * 4);
  int* epos = (int*)alloc((size_t)N_EDGES * 4);
  int* rowptr = (int*)alloc((size_t)(N_NODES + 1) * 4);
  int* stmp = (int*)alloc((size_t)N_NODES * 4);
  int* bsum = (int*)alloc(64 * 4);
  int* csr_src = (int*)alloc((size_t)N_EDGES * 4);
  bf16* xp = (bf16*)alloc((size_t)N_NODES * 256 * 2);
  bf16* hm0 = (bf16*)alloc((size_t)N_NODES * 256 * 2);

  CvtJobs jobs;
  int ji = 0;
  auto addjob = [&](const void* s, float* d, int n) {
    jobs.src[ji] = s; jobs.dst[ji] = d; jobs.n[ji] = n; ji++;
  };
  addjob(d_in[5], W_peg_f, 1024);
  addjob(d_in[6], b_peg_f, 32);
  addjob(d_in[8], a_s0_f, 256);
  addjob(d_in[9], a_d0_f, 256);
  addjob(d_in[10], w_pe0_f, 4);
  addjob(d_in[11], W_u0_f, 1024);
  addjob(d_in[13], a_s1_f, 256);
  addjob(d_in[14], a_d1_f, 256);
  addjob(d_in[15], w_pe1_f, 4);
  addjob(d_in[16], W_u1_f, 1024);

  // zero deg before prep's histogram atomics
  hipMemsetAsync(deg, 0, (size_t)N_NODES * 4, stream);

  // prep (detect+cvt+transposes, blocks 0-399) + histogram+epos (blocks 400+)
  prep_kernel<<<400 + NCHUNK, 256, 0, stream>>>(
      jobs, (const unsigned short*)d_in[5], d_in[7], Wt0, d_in[12], Wt1, flag,
      dst, deg, epos);

  scan1_kernel<<<49, 1024, 0, stream>>>(deg, stmp, bsum, N_NODES);
  scan3_kernel<<<49, 1024, 0, stream>>>(stmp, bsum, rowptr, N_NODES, 49);

  // XCD-partitioned atomic-free CSR fill (25000) + PEG chains (12500)
  fill_peg_kernel<<<NFILL8 + 2 * NDIV8, 256, 0, stream>>>(
      src, dst, rowptr, epos, csr_src, PE_noise, PE, W_peg_f, b_peg_f, W_u0_f,
      W_u1_f, d_out, (size_t)N_NODES * 256, blob0, blob1, flag);

  // XCD-grouped 1D grid: ceil(nrt/8)*8 row-tiles * 4 col-tiles
  int nrt = (N_NODES + 63) / 64;
  int gblk = ((nrt + 7) / 8) * 8 * 4;

  // ---- GAT layer 0 (A = x_masked dual, K=128); al fused into gemm epilogue
  mfma_gemm<128, true><<<gblk, 256, 0, stream>>>(x_masked, Wt0, xp, N_NODES,
                                                 a_s0_f, a_d0_f, blob0, al_d, flag);
  agg_kernel<true, false><<<N_NODES / 4, 256, 0, stream>>>(
      xp, blob0, al_d, w_pe0_f, csr_src, rowptr, hm0, flag);

  // ---- GAT layer 1 (A = hm0 bf16, K=256)
  mfma_gemm<256, false><<<gblk, 256, 0, stream>>>(hm0, Wt1, xp, N_NODES,
                                                  a_s1_f, a_d1_f, blob1, al_d, flag);
  agg_kernel<false, true><<<N_NODES / 4, 256, 0, stream>>>(
      xp, blob1, al_d, w_pe1_f, csr_src, rowptr, d_out, flag);
}